// Round 3
// baseline (29.962 us; speedup 1.0000x reference)
//
#include <hip/hip_runtime.h>

#define B_  4
#define QL  128
#define CL  512
#define XD  64
#define ED  128
#define DD  128
#define YD  32

typedef __attribute__((ext_vector_type(8))) _Float16 f16x8;
typedef __attribute__((ext_vector_type(4))) float f32x4;

// ws layout (16B-aligned):
//   fph : f16 [B_*CL*DD] = 512 KB   f-part of relu input
//   qph : f16 [B_*QL*DD] = 128 KB   q-part + b0
//   w1f : f16 [16384]    =  32 KB   W1 B-fragments [wcol][kk][jt][lane][e]
__global__ void prep_kernel(const float* __restrict__ q,
                            const float* __restrict__ f,
                            const float* __restrict__ W0,
                            const float* __restrict__ b0,
                            const float* __restrict__ W1,
                            _Float16* __restrict__ fph,
                            _Float16* __restrict__ qph,
                            _Float16* __restrict__ w1f) {
  const int bid = blockIdx.x, tid = threadIdx.x;
  __shared__ __align__(16) float fr[128][20];   // [e][row], pad 20 keeps 16B align + banks spread

  if (bid < 128) {
    // ---- fp: 16 rows per block. fp[r][d] = sum_e f[r][e]*W0[XD+e][d] ----
    const int r0 = bid * 16;
    #pragma unroll
    for (int i = 0; i < 8; ++i) {
      int idx = i * 256 + tid;          // 0..2047
      fr[idx & 127][idx >> 7] = f[((size_t)r0 + (idx >> 7)) * ED + (idx & 127)];
    }
    __syncthreads();
    const int d = tid & 127, half = tid >> 7;
    float acc[8] = {};
    const float* w = W0 + XD * DD + d;
    for (int e = 0; e < ED; ++e) {
      float wv = w[e * DD];
      f32x4 f0 = *(const f32x4*)&fr[e][half * 8];
      f32x4 f1 = *(const f32x4*)&fr[e][half * 8 + 4];
      #pragma unroll
      for (int j = 0; j < 4; ++j) {
        acc[j]     = fmaf(f0[j], wv, acc[j]);
        acc[j + 4] = fmaf(f1[j], wv, acc[j + 4]);
      }
    }
    #pragma unroll
    for (int j = 0; j < 8; ++j)
      fph[((size_t)r0 + half * 8 + j) * DD + d] = (_Float16)acc[j];
  } else if (bid < 160) {
    // ---- qp: 16 rows per block. qp[r][d] = b0[d] + sum_x q[r][x]*W0[x][d] ----
    const int r0 = (bid - 128) * 16;
    #pragma unroll
    for (int i = 0; i < 4; ++i) {
      int idx = i * 256 + tid;          // 0..1023
      fr[idx & 63][idx >> 6] = q[((size_t)r0 + (idx >> 6)) * XD + (idx & 63)];
    }
    __syncthreads();
    const int d = tid & 127, half = tid >> 7;
    float acc[8];
    float bv = b0[d];
    #pragma unroll
    for (int j = 0; j < 8; ++j) acc[j] = bv;
    const float* w = W0 + d;
    for (int e = 0; e < XD; ++e) {
      float wv = w[e * DD];
      f32x4 f0 = *(const f32x4*)&fr[e][half * 8];
      f32x4 f1 = *(const f32x4*)&fr[e][half * 8 + 4];
      #pragma unroll
      for (int j = 0; j < 4; ++j) {
        acc[j]     = fmaf(f0[j], wv, acc[j]);
        acc[j + 4] = fmaf(f1[j], wv, acc[j + 4]);
      }
    }
    #pragma unroll
    for (int j = 0; j < 8; ++j)
      qph[((size_t)r0 + half * 8 + j) * DD + d] = (_Float16)acc[j];
  } else {
    // ---- W1 B-fragments: idx = (((wcol*4+kk)*4+jt)*64+lane)*8+e
    //      val = W1[k][col], col = wcol*64+jt*16+(lane&15), k = kk*32+(lane>>4)*8+e
    #pragma unroll 8
    for (int i = 0; i < 64; ++i) {
      int idx = i * 256 + tid;
      int e = idx & 7, lane = (idx >> 3) & 63, jt = (idx >> 9) & 3;
      int kk = (idx >> 11) & 3, wcol = (idx >> 13) & 1;
      int col = wcol * 64 + jt * 16 + (lane & 15);
      int k = kk * 32 + (lane >> 4) * 8 + e;
      w1f[idx] = (_Float16)W1[k * DD + col];
    }
  }
}

__launch_bounds__(256, 2)
__global__ void main_kernel(const float* __restrict__ logits,
                            const _Float16* __restrict__ fph,
                            const _Float16* __restrict__ qph,
                            const _Float16* __restrict__ w1f,
                            const float* __restrict__ b1,
                            const float* __restrict__ Wo,
                            const float* __restrict__ bo,
                            float* __restrict__ out) {
  __shared__ float att[CL];
  __shared__ float g[4][DD];
  __shared__ float red[8];
  __shared__ float part[8][YD];

  const int tid = threadIdx.x;
  const int bid = blockIdx.x;          // b*QL + qi
  const int wid = tid >> 6;
  const int ln  = tid & 63;
  const int b   = bid >> 7;
  const int wcol = wid & 1, wrow = wid >> 1;
  const int lhi = ln >> 4, llo = ln & 15;

  // ---- W1 B-fragments -> registers (16 coalesced dwordx4) ----
  f16x8 wf[4][4];
  {
    const uint4* ws = (const uint4*)w1f;
    #pragma unroll
    for (int kk = 0; kk < 4; ++kk)
      #pragma unroll
      for (int jt = 0; jt < 4; ++jt) {
        uint4 v = ws[(((wcol * 4 + kk) * 4 + jt) << 6) + ln];
        wf[kk][jt] = *(const f16x8*)&v;
      }
  }
  // ---- qp fragment slices: qpv[kk] = qph[bid][kk*32 + lhi*8 ..+8] (broadcast loads) ----
  f16x8 qpv[4];
  {
    const uint4* qs = (const uint4*)(qph + (size_t)bid * DD);
    #pragma unroll
    for (int kk = 0; kk < 4; ++kk) {
      uint4 v = qs[kk * 2 + (lhi >> 1) * 0 + 0];   // placeholder overwritten below
      (void)v;
      uint4 u = qs[(kk * 32 + lhi * 8) >> 3];
      qpv[kk] = *(const f16x8*)&u;
    }
  }

  ((float*)g)[tid] = 0.f;
  ((float*)g)[tid + 256] = 0.f;

  // ---- softmax over 512 logits ----
  {
    const float* lg = logits + (size_t)bid * CL;
    float l0 = lg[tid], l1 = lg[tid + 256];
    float m = fmaxf(l0, l1);
    #pragma unroll
    for (int off = 1; off < 64; off <<= 1) m = fmaxf(m, __shfl_xor(m, off, 64));
    if (ln == 0) red[wid] = m;
    __syncthreads();
    m = fmaxf(fmaxf(red[0], red[1]), fmaxf(red[2], red[3]));
    float p0 = expf(l0 - m), p1 = expf(l1 - m);
    float s = p0 + p1;
    #pragma unroll
    for (int off = 1; off < 64; off <<= 1) s += __shfl_xor(s, off, 64);
    if (ln == 0) red[4 + wid] = s;
    __syncthreads();
    float inv = 1.f / (red[4] + red[5] + red[6] + red[7]);
    att[tid] = p0 * inv;
    att[tid + 256] = p1 * inv;
  }
  __syncthreads();   // att visible to all waves; NO barriers after this

  const int j0 = wcol * 64 + llo;
  float b1v[4];
  #pragma unroll
  for (int jt = 0; jt < 4; ++jt) b1v[jt] = b1[j0 + jt * 16];
  float gp[4] = {0.f, 0.f, 0.f, 0.f};

  // per-lane A base: row = wrow*64 + llo, k-slice base = lhi*8
  const _Float16* abase = fph + ((size_t)b * CL) * DD + ((size_t)(wrow * 64 + llo)) * DD + lhi * 8;
  const f16x8 zf = {};

  // ---- 4 c-tiles, barrier-free: A gathered straight from global (L1/L2) ----
  #pragma unroll
  for (int t = 0; t < 4; ++t) {
    f32x4 acc[4][4];
    #pragma unroll
    for (int ct = 0; ct < 4; ++ct)
      #pragma unroll
      for (int jt = 0; jt < 4; ++jt) acc[ct][jt] = (f32x4){0.f, 0.f, 0.f, 0.f};

    const _Float16* at = abase + (size_t)t * 128 * DD;
    #pragma unroll
    for (int kk = 0; kk < 4; ++kk) {
      f16x8 a[4];
      #pragma unroll
      for (int ct = 0; ct < 4; ++ct) {
        uint4 v = *(const uint4*)(at + (size_t)ct * 16 * DD + kk * 32);
        f16x8 x = *(const f16x8*)&v + qpv[kk];               // v_pk_add_f16
        a[ct] = __builtin_elementwise_max(x, zf);            // v_pk_max_f16 (relu)
      }
      #pragma unroll
      for (int ct = 0; ct < 4; ++ct)
        #pragma unroll
        for (int jt = 0; jt < 4; ++jt)
          acc[ct][jt] = __builtin_amdgcn_mfma_f32_16x16x32_f16(a[ct], wf[kk][jt], acc[ct][jt], 0, 0, 0);
    }

    // epilogue: g[j] += att[c] * relu(H2 + b1)   (Wo GEMM commuted away)
    const int cbase = t * 128 + wrow * 64 + lhi * 4;
    #pragma unroll
    for (int ct = 0; ct < 4; ++ct) {
      f32x4 a4 = *(const f32x4*)&att[cbase + ct * 16];
      #pragma unroll
      for (int r = 0; r < 4; ++r) {
        #pragma unroll
        for (int jt = 0; jt < 4; ++jt) {
          float h = fmaxf(acc[ct][jt][r] + b1v[jt], 0.f);
          gp[jt] = fmaf(a4[r], h, gp[jt]);
        }
      }
    }
  }

  // reduce gp across the 4 row-groups (cols identical across lhi)
  #pragma unroll
  for (int jt = 0; jt < 4; ++jt) {
    gp[jt] += __shfl_xor(gp[jt], 16, 64);
    gp[jt] += __shfl_xor(gp[jt], 32, 64);
  }
  if (ln < 16) {
    #pragma unroll
    for (int jt = 0; jt < 4; ++jt) g[wid][j0 + jt * 16] = gp[jt];
  }
  __syncthreads();

  // ---- y = g @ Wo + bo (fp32, tiny) ----
  {
    int y = tid & 31, ch = tid >> 5;
    float a = 0.f;
    #pragma unroll
    for (int jj = 0; jj < 16; ++jj) {
      int j = ch * 16 + jj;
      float gj = g[0][j] + g[1][j] + g[2][j] + g[3][j];
      a = fmaf(gj, Wo[j * YD + y], a);
    }
    part[ch][y] = a;
  }
  __syncthreads();
  if (tid < YD) {
    float a = bo[tid];
    #pragma unroll
    for (int ch = 0; ch < 8; ++ch) a += part[ch][tid];
    out[(size_t)bid * YD + tid] = a;
  }
}

extern "C" void kernel_launch(void* const* d_in, const int* in_sizes, int n_in,
                              void* d_out, int out_size, void* d_ws, size_t ws_size,
                              hipStream_t stream) {
  const float* q  = (const float*)d_in[0];
  const float* f  = (const float*)d_in[1];
  const float* lg = (const float*)d_in[2];
  const float* W0 = (const float*)d_in[3];
  const float* b0 = (const float*)d_in[4];
  const float* W1 = (const float*)d_in[5];
  const float* b1 = (const float*)d_in[6];
  const float* Wo = (const float*)d_in[7];
  const float* bo = (const float*)d_in[8];
  float* out = (float*)d_out;

  _Float16* fph = (_Float16*)d_ws;                       // 512 KB
  _Float16* qph = fph + (size_t)B_ * CL * DD;            // 128 KB
  _Float16* w1f = qph + (size_t)B_ * QL * DD;            //  32 KB

  prep_kernel<<<161, 256, 0, stream>>>(q, f, W0, b0, W1, fph, qph, w1f);
  main_kernel<<<B_ * QL, 256, 0, stream>>>(lg, fph, qph, w1f, b1, Wo, bo, out);
}

// Round 5
// 23.689 us; speedup vs baseline: 1.2648x; 1.2648x over previous
//
#include <hip/hip_runtime.h>

#define B_  4
#define QL  128
#define CL  512
#define XD  64
#define ED  128
#define DD  128
#define YD  32

typedef __attribute__((ext_vector_type(8))) _Float16 f16x8;
typedef __attribute__((ext_vector_type(4))) float f32x4;

// ws layout (16B-aligned):
//   fph : f16 [512 chunks][64 lanes][8 e] = 512 KB  fragment-ordered f-part
//         chunk = ((b*4+t)*4+kk)*8 + wrow*4 + ct ; holds
//         fp[b][t*128+wrow*64+ct*16+llo][kk*32+lhi*8+e] at lane lhi*16+llo, elem e
//   qph : f16 [B_*QL*DD] = 128 KB  q-part + b0, linear [row][d]
//   w1f : f16 [16384]    =  32 KB  W1 B-fragments [wcol][kk][jt][lane][e]
__global__ void prep_kernel(const float* __restrict__ qg,
                            const float* __restrict__ fg,
                            const float* __restrict__ W0,
                            const float* __restrict__ b0,
                            const float* __restrict__ W1,
                            _Float16* __restrict__ fph,
                            _Float16* __restrict__ qph,
                            _Float16* __restrict__ w1f) {
  const int bid = blockIdx.x, tid = threadIdx.x;
  __shared__ __align__(16) float fr[128][20];
  __shared__ float w1s[32][65];

  if (bid < 128) {
    // ---- fp: 16 global rows per block, fragment-ordered store ----
    const int r0 = bid * 16;
    #pragma unroll
    for (int i = 0; i < 8; ++i) {
      int idx = i * 256 + tid;
      fr[idx & 127][idx >> 7] = fg[((size_t)r0 + (idx >> 7)) * ED + (idx & 127)];
    }
    __syncthreads();
    const int d = tid & 127, half = tid >> 7;
    float acc[8] = {};
    const float* w = W0 + XD * DD + d;
    for (int e = 0; e < ED; ++e) {
      float wv = w[e * DD];
      f32x4 f0 = *(const f32x4*)&fr[e][half * 8];
      f32x4 f1 = *(const f32x4*)&fr[e][half * 8 + 4];
      #pragma unroll
      for (int j = 0; j < 4; ++j) {
        acc[j]     = fmaf(f0[j], wv, acc[j]);
        acc[j + 4] = fmaf(f1[j], wv, acc[j + 4]);
      }
    }
    const int kk = d >> 5, lhi = (d >> 3) & 3, e2 = d & 7;
    #pragma unroll
    for (int j = 0; j < 8; ++j) {
      int R = r0 + half * 8 + j;          // global row = b*CL + c
      int b = R >> 9, c = R & 511;
      int t = c >> 7, cc = c & 127;
      int chunk = ((b * 4 + t) * 4 + kk) * 8 + (cc >> 6) * 4 + ((cc >> 4) & 3);
      fph[((size_t)chunk << 9) + ((size_t)(lhi * 16 + (cc & 15)) << 3) + e2] = (_Float16)acc[j];
    }
  } else if (bid < 160) {
    // ---- qp: 16 rows per block, linear store (b0 folded) ----
    const int r0 = (bid - 128) * 16;
    #pragma unroll
    for (int i = 0; i < 4; ++i) {
      int idx = i * 256 + tid;
      fr[idx & 63][idx >> 6] = qg[((size_t)r0 + (idx >> 6)) * XD + (idx & 63)];
    }
    __syncthreads();
    const int d = tid & 127, half = tid >> 7;
    float acc[8];
    float bv = b0[d];
    #pragma unroll
    for (int j = 0; j < 8; ++j) acc[j] = bv;
    const float* w = W0 + d;
    for (int e = 0; e < XD; ++e) {
      float wv = w[e * DD];
      f32x4 f0 = *(const f32x4*)&fr[e][half * 8];
      f32x4 f1 = *(const f32x4*)&fr[e][half * 8 + 4];
      #pragma unroll
      for (int j = 0; j < 4; ++j) {
        acc[j]     = fmaf(f0[j], wv, acc[j]);
        acc[j + 4] = fmaf(f1[j], wv, acc[j + 4]);
      }
    }
    #pragma unroll
    for (int j = 0; j < 8; ++j)
      qph[((size_t)r0 + half * 8 + j) * DD + d] = (_Float16)acc[j];
  } else {
    // ---- w1f: 8 blocks, LDS-staged coalesced fragment build ----
    const int id8 = bid - 160;            // 0..7
    const int wcol = id8 & 1, kk = id8 >> 1;
    #pragma unroll
    for (int i = 0; i < 8; ++i) {
      int idx = i * 256 + tid;            // 32 k-rows x 64 cols
      w1s[idx >> 6][idx & 63] = W1[(kk * 32 + (idx >> 6)) * DD + wcol * 64 + (idx & 63)];
    }
    __syncthreads();
    const int jt = tid >> 6, ln = tid & 63;
    const int llo = ln & 15, lhi = ln >> 4;
    f16x8 v;
    #pragma unroll
    for (int e = 0; e < 8; ++e)
      v[e] = (_Float16)w1s[lhi * 8 + e][jt * 16 + llo];
    *(f16x8*)(w1f + ((((size_t)wcol * 4 + kk) * 4 + jt) * 64 + ln) * 8) = v;
  }
}

__launch_bounds__(256, 2)
__global__ void main_kernel(const float* __restrict__ logits,
                            const _Float16* __restrict__ fph,
                            const _Float16* __restrict__ qph,
                            const _Float16* __restrict__ w1f,
                            const float* __restrict__ b1,
                            const float* __restrict__ Wo,
                            const float* __restrict__ bo,
                            float* __restrict__ out) {
  __shared__ __align__(16) float att[CL];
  __shared__ float g[4][DD];
  __shared__ float red[8];
  __shared__ float part[8][YD];

  const int tid = threadIdx.x;
  const int bid = blockIdx.x;          // b*QL + qi
  const int wid = tid >> 6, ln = tid & 63;
  const int b = bid >> 7;
  const int wrow = wid >> 1, wcol = wid & 1;
  const int lhi = ln >> 4, llo = ln & 15;

  ((float*)g)[tid] = 0.f;
  ((float*)g)[tid + 256] = 0.f;

  // ---- W1 fragments -> registers (16 coalesced dwordx4, L2-broadcast) ----
  f16x8 wf[4][4];
  {
    const uint4* ws = (const uint4*)w1f;
    #pragma unroll
    for (int kk = 0; kk < 4; ++kk)
      #pragma unroll
      for (int jt = 0; jt < 4; ++jt) {
        uint4 u = ws[(((wcol * 4 + kk) * 4 + jt) << 6) + ln];
        wf[kk][jt] = *(const f16x8*)&u;
      }
  }
  // ---- qp fragment slices (broadcast 16B loads) ----
  f16x8 qpv[4];
  {
    const uint4* qs = (const uint4*)(qph + (size_t)bid * DD);
    #pragma unroll
    for (int kk = 0; kk < 4; ++kk) {
      uint4 u = qs[(kk * 32 + lhi * 8) >> 3];
      qpv[kk] = *(const f16x8*)&u;
    }
  }

  // ---- softmax over 512 logits ----
  {
    const float* lgr = logits + (size_t)bid * CL;
    float l0 = lgr[tid], l1 = lgr[tid + 256];
    float m = fmaxf(l0, l1);
    #pragma unroll
    for (int off = 1; off < 64; off <<= 1) m = fmaxf(m, __shfl_xor(m, off, 64));
    if (ln == 0) red[wid] = m;
    __syncthreads();
    m = fmaxf(fmaxf(red[0], red[1]), fmaxf(red[2], red[3]));
    float p0 = expf(l0 - m), p1 = expf(l1 - m);
    float s = p0 + p1;
    #pragma unroll
    for (int off = 1; off < 64; off <<= 1) s += __shfl_xor(s, off, 64);
    if (ln == 0) red[4 + wid] = s;
    __syncthreads();
    float inv = 1.f / (red[4] + red[5] + red[6] + red[7]);
    att[tid] = p0 * inv;
    att[tid + 256] = p1 * inv;
  }
  __syncthreads();   // att visible; no more barriers until output

  const int j0 = wcol * 64 + llo;
  float b1v[4];
  #pragma unroll
  for (int jt = 0; jt < 4; ++jt) b1v[jt] = b1[j0 + jt * 16];

  float gp[4] = {0.f, 0.f, 0.f, 0.f};
  const f16x8 zf = {};
  const uint4* fpv = (const uint4*)fph;

  #pragma unroll
  for (int t = 0; t < 4; ++t) {
    f32x4 acc[4][4];
    #pragma unroll
    for (int ct = 0; ct < 4; ++ct)
      #pragma unroll
      for (int jt = 0; jt < 4; ++jt)
        acc[ct][jt] = (f32x4){b1v[jt], b1v[jt], b1v[jt], b1v[jt]};   // b1 folded

    #pragma unroll
    for (int kk = 0; kk < 4; ++kk) {
      const int cb = ((((b * 4 + t) * 4 + kk) * 8 + wrow * 4) << 6);
      f16x8 a[4];
      #pragma unroll
      for (int ct = 0; ct < 4; ++ct) {
        uint4 u = fpv[cb + (ct << 6) + ln];                  // coalesced 1KB/wave
        f16x8 x = *(const f16x8*)&u + qpv[kk];               // v_pk_add_f16
        a[ct] = __builtin_elementwise_max(x, zf);            // relu
      }
      #pragma unroll
      for (int ct = 0; ct < 4; ++ct)
        #pragma unroll
        for (int jt = 0; jt < 4; ++jt)
          acc[ct][jt] = __builtin_amdgcn_mfma_f32_16x16x32_f16(a[ct], wf[kk][jt], acc[ct][jt], 0, 0, 0);
    }

    // epilogue: g[j] += att[c] * relu(H2)  (Wo GEMM commuted away; b1 in acc)
    const int cbase = t * 128 + wrow * 64 + lhi * 4;
    #pragma unroll
    for (int ct = 0; ct < 4; ++ct) {
      f32x4 a4 = *(const f32x4*)&att[cbase + ct * 16];
      #pragma unroll
      for (int r = 0; r < 4; ++r)
        #pragma unroll
        for (int jt = 0; jt < 4; ++jt)
          gp[jt] = fmaf(a4[r], fmaxf(acc[ct][jt][r], 0.f), gp[jt]);
    }
  }

  // reduce over lhi groups (same column j), then cross-wave via LDS
  #pragma unroll
  for (int jt = 0; jt < 4; ++jt) {
    gp[jt] += __shfl_xor(gp[jt], 16, 64);
    gp[jt] += __shfl_xor(gp[jt], 32, 64);
  }
  __syncthreads();
  if (ln < 16) {
    #pragma unroll
    for (int jt = 0; jt < 4; ++jt) g[wid][j0 + jt * 16] = gp[jt];
  }
  __syncthreads();

  // ---- y = g @ Wo + bo ----
  {
    int y = tid & 31, ch = tid >> 5;
    float a = 0.f;
    #pragma unroll
    for (int jj = 0; jj < 16; ++jj) {
      int j = ch * 16 + jj;
      float gj = g[0][j] + g[1][j] + g[2][j] + g[3][j];
      a = fmaf(gj, Wo[j * YD + y], a);
    }
    part[ch][y] = a;
  }
  __syncthreads();
  if (tid < YD) {
    float a = bo[tid];
    #pragma unroll
    for (int ch = 0; ch < 8; ++ch) a += part[ch][tid];
    out[(size_t)bid * YD + tid] = a;
  }
}

extern "C" void kernel_launch(void* const* d_in, const int* in_sizes, int n_in,
                              void* d_out, int out_size, void* d_ws, size_t ws_size,
                              hipStream_t stream) {
  const float* q  = (const float*)d_in[0];
  const float* f  = (const float*)d_in[1];
  const float* lg = (const float*)d_in[2];
  const float* W0 = (const float*)d_in[3];
  const float* b0 = (const float*)d_in[4];
  const float* W1 = (const float*)d_in[5];
  const float* b1 = (const float*)d_in[6];
  const float* Wo = (const float*)d_in[7];
  const float* bo = (const float*)d_in[8];
  float* out = (float*)d_out;

  _Float16* fph = (_Float16*)d_ws;                         // 512 KB
  _Float16* qph = fph + (size_t)512 * 512;                 // 128 KB
  _Float16* w1f = qph + (size_t)B_ * QL * DD;              //  32 KB

  prep_kernel<<<168, 256, 0, stream>>>(q, f, W0, b0, W1, fph, qph, w1f);
  main_kernel<<<B_ * QL, 256, 0, stream>>>(lg, fph, qph, w1f, b1, Wo, bo, out);
}